// Round 5
// baseline (412.164 us; speedup 1.0000x reference)
//
#include <hip/hip_runtime.h>

#define HID 32
#define CAP 32        // bucket capacity; indegree ~ Poisson(4), P(deg>32) ~ 1e-19
#define WPAD 20       // padded inner dim (floats): o*20 mod 32 covers all 8 bank-groups
#define PSTRIDE 1280  // LDS plane stride in floats = 2 halves * 32 o * WPAD

// ---- build dst-bucketed edge permutation (one pass, int atomics only) ----
__global__ __launch_bounds__(256) void build_kernel(
    const int* __restrict__ src, const int* __restrict__ dst,
    const float* __restrict__ ea,
    int* __restrict__ deg, int* __restrict__ perm_src, float4* __restrict__ perm_ea,
    int E)
{
    int e = blockIdx.x * blockDim.x + threadIdx.x;
    if (e >= E) return;
    int d = dst[e];
    int pos = atomicAdd(deg + d, 1) & (CAP - 1);    // mask: memory-safe even on impossible overflow
    size_t slot = (size_t)d * CAP + pos;
    perm_src[slot] = src[e];
    perm_ea[slot]  = *(const float4*)(ea + (size_t)e * 4);
}

// ---- 4-input-channel quad of the fused edge-MLP + msg dot ----
// t_i = relu(ea . w[:,i,o] + b[i,o]);  acc += x_i * t_i   for 4 consecutive i
__device__ __forceinline__ float edge_quad(const float4 av, const float4 xv,
                                           const float4 WA, const float4 WB,
                                           const float4 WC, const float4 WD,
                                           const float4 BR, float acc)
{
    float t;
    t = fmaf(av.x, WA.x, BR.x); t = fmaf(av.y, WB.x, t); t = fmaf(av.z, WC.x, t); t = fmaf(av.w, WD.x, t);
    acc = fmaf(xv.x, fmaxf(t, 0.f), acc);
    t = fmaf(av.x, WA.y, BR.y); t = fmaf(av.y, WB.y, t); t = fmaf(av.z, WC.y, t); t = fmaf(av.w, WD.y, t);
    acc = fmaf(xv.y, fmaxf(t, 0.f), acc);
    t = fmaf(av.x, WA.z, BR.z); t = fmaf(av.y, WB.z, t); t = fmaf(av.z, WC.z, t); t = fmaf(av.w, WD.z, t);
    acc = fmaf(xv.z, fmaxf(t, 0.f), acc);
    t = fmaf(av.x, WA.w, BR.w); t = fmaf(av.y, WB.w, t); t = fmaf(av.z, WC.w, t); t = fmaf(av.w, WD.w, t);
    acc = fmaf(xv.w, fmaxf(t, 0.f), acc);
    return acc;
}

// ---- layer-1 pull (IN=8): 64-lane wave per node; o = lane&31, half = lane>>5
// owns input channels half*4..half*4+3. Weight state = 6 float4 = 24 regs ->
// pure-register, high occupancy. 4-neighbor batches; halves combined by shfl.
__global__ __launch_bounds__(256, 4) void pull8_kernel(
    const float* __restrict__ x,                    // [N, 8]
    const int* __restrict__ deg,
    const int* __restrict__ perm_src, const float4* __restrict__ perm_ea,
    const float* __restrict__ w_mlp,                // [4, 8*HID]
    const float* __restrict__ b_mlp,                // [8*HID]
    const float* __restrict__ root,                 // [8, HID]
    const float* __restrict__ bias,                 // [HID]
    float* __restrict__ h_out,                      // [N, HID]
    int N)
{
    constexpr int IN = 8, NPG = 8;
    const int lane = threadIdx.x & 63;
    const int o = lane & 31, half = lane >> 5;
    const int wave = (blockIdx.x * blockDim.x + threadIdx.x) >> 6;
    const int v0 = wave * NPG;
    if (v0 >= N) return;

    const int cb = half * 4 * HID + o;              // i = half*4 + {0..3}; coalesced per load
    const float4 WA = make_float4(w_mlp[cb],       w_mlp[cb+32],       w_mlp[cb+64],       w_mlp[cb+96]);
    const float4 WB = make_float4(w_mlp[256+cb],   w_mlp[256+cb+32],   w_mlp[256+cb+64],   w_mlp[256+cb+96]);
    const float4 WC = make_float4(w_mlp[512+cb],   w_mlp[512+cb+32],   w_mlp[512+cb+64],   w_mlp[512+cb+96]);
    const float4 WD = make_float4(w_mlp[768+cb],   w_mlp[768+cb+32],   w_mlp[768+cb+64],   w_mlp[768+cb+96]);
    const float4 BR = make_float4(b_mlp[cb],       b_mlp[cb+32],       b_mlp[cb+64],       b_mlp[cb+96]);
    const float4 RO = make_float4(root[cb],        root[cb+32],        root[cb+64],        root[cb+96]);
    const float bo = bias[o];

    for (int nv = 0; nv < NPG; ++nv) {
        const int v = v0 + nv;
        if (v >= N) break;
        const int dt = deg[v];
        const int dg = min(dt, CAP);
        const int* ps = perm_src + (size_t)v * CAP;
        const float4* pe = perm_ea + (size_t)v * CAP;

        float acc = 0.f;
        for (int k0 = 0; k0 < dg; k0 += 4) {
            int4 s4 = *(const int4*)(ps + k0);
            int ss[4] = { s4.x, s4.y, s4.z, s4.w };
            float4 aa[4];
            #pragma unroll
            for (int j = 0; j < 4; ++j) {
                aa[j] = pe[k0 + j];                 // tail slots: garbage, gated below
                if (k0 + j >= dg) ss[j] = 0;
            }
            float4 xg[4];
            #pragma unroll
            for (int j = 0; j < 4; ++j)
                xg[j] = *(const float4*)(x + (size_t)ss[j] * IN + half * 4);
            #pragma unroll
            for (int j = 0; j < 4; ++j)
                if (k0 + j < dg)                    // wave-uniform
                    acc = edge_quad(aa[j], xg[j], WA, WB, WC, WD, BR, acc);
        }
        const float4 xr = *(const float4*)(x + (size_t)v * IN + half * 4);
        float rpart = fmaf(xr.x, RO.x, fmaf(xr.y, RO.y, fmaf(xr.z, RO.z, xr.w * RO.w)));
        float part = acc / fmaxf((float)dt, 1.f) + rpart;
        part += __shfl_down(part, 32);              // combine halves
        if (lane < 32)
            h_out[(size_t)v * HID + o] = fmaxf(part + bo, 0.f);
    }
}

// ---- layers 2/3 pull (IN=32): 64-lane wave per node; o = lane&31, half = lane>>5
// owns 16 input channels. Weights live in LDS (staged once per block), read per
// 4-i chunk (5x ds_read_b128, conflict-free via WPAD=20) and amortized over a
// 4-neighbor batch -> only ~20 weight regs live at a time, no reloads/spills.
// HEAD fuses conv3 node update + output MLP (head weights also in LDS).
template<bool HEAD>
__global__ __launch_bounds__(256, 4) void pull32_kernel(
    const float* __restrict__ h_in,                 // [N, 32]
    const int* __restrict__ deg,
    const int* __restrict__ perm_src, const float4* __restrict__ perm_ea,
    const float* __restrict__ w_mlp,                // [4, 32*HID]
    const float* __restrict__ b_mlp,                // [32*HID]
    const float* __restrict__ root,                 // [32, HID]
    const float* __restrict__ bias,                 // [HID]
    const float* __restrict__ hw1, const float* __restrict__ hb1,  // head
    const float* __restrict__ hw2, const float* __restrict__ hb2,  // head
    float* __restrict__ h_out,                      // [N, HID] or [N] if HEAD
    int N)
{
    constexpr int IN = 32, NPW = 8;
    // planes 0-3: w_mlp[c]; 4: b_mlp; 5: root. widx = ((p*2+half)*32+o)*WPAD + i
    // head block at 7680: hw1[32*32], hb1 @8704, hw2 @8736
    __shared__ __align__(16) float lw[8768];
    for (int t = threadIdx.x; t < 4096; t += 256) {
        int c = t >> 10, rem = t & 1023, i = rem >> 5, oo = rem & 31;
        lw[((c * 2 + (i >> 4)) * 32 + oo) * WPAD + (i & 15)] = w_mlp[t];
    }
    for (int t = threadIdx.x; t < 1024; t += 256) {
        int i = t >> 5, oo = t & 31;
        lw[((8  + (i >> 4)) * 32 + oo) * WPAD + (i & 15)] = b_mlp[t];
        lw[((10 + (i >> 4)) * 32 + oo) * WPAD + (i & 15)] = root[t];
    }
    if (HEAD) {
        for (int t = threadIdx.x; t < 1024; t += 256) lw[7680 + t] = hw1[t];
        if (threadIdx.x < 32) {
            lw[8704 + threadIdx.x] = hb1[threadIdx.x];
            lw[8736 + threadIdx.x] = hw2[threadIdx.x];
        }
    }
    __syncthreads();

    const int lane = threadIdx.x & 63;
    const int o = lane & 31, half = lane >> 5;
    const int wave = (blockIdx.x * blockDim.x + threadIdx.x) >> 6;
    const int v0 = wave * NPW;
    if (v0 >= N) return;

    const float* wp = lw + ((half << 5) + o) * WPAD;   // this lane's weight column base
    const float bo = bias[o];
    float hb2v = 0.f;
    if (HEAD) hb2v = hb2[0];

    for (int nv = 0; nv < NPW; ++nv) {
        const int v = v0 + nv;
        if (v >= N) break;
        const int dt = deg[v];
        const int dg = min(dt, CAP);
        const int* ps = perm_src + (size_t)v * CAP;
        const float4* pe = perm_ea + (size_t)v * CAP;

        float acc = 0.f;
        for (int k0 = 0; k0 < dg; k0 += 4) {
            int4 s4 = *(const int4*)(ps + k0);
            int ss[4] = { s4.x, s4.y, s4.z, s4.w };
            float4 aa[4];
            #pragma unroll
            for (int j = 0; j < 4; ++j) {
                aa[j] = pe[k0 + j];                 // tail slots: garbage, gated below
                if (k0 + j >= dg) ss[j] = 0;
            }
            // gather 4 neighbor half-rows (2 distinct 64B segments per wave)
            float4 xg[4][4];
            #pragma unroll
            for (int j = 0; j < 4; ++j) {
                const float* xp = h_in + (size_t)ss[j] * IN + (half << 4);
                xg[j][0] = *(const float4*)(xp);
                xg[j][1] = *(const float4*)(xp + 4);
                xg[j][2] = *(const float4*)(xp + 8);
                xg[j][3] = *(const float4*)(xp + 12);
            }
            // chunked weights from LDS, each chunk amortized over the 4 neighbors
            #pragma unroll
            for (int k = 0; k < 4; ++k) {
                const float4 WA = *(const float4*)(wp + 4 * k);
                const float4 WB = *(const float4*)(wp + PSTRIDE     + 4 * k);
                const float4 WC = *(const float4*)(wp + 2 * PSTRIDE + 4 * k);
                const float4 WD = *(const float4*)(wp + 3 * PSTRIDE + 4 * k);
                const float4 BR = *(const float4*)(wp + 4 * PSTRIDE + 4 * k);
                #pragma unroll
                for (int j = 0; j < 4; ++j)
                    if (k0 + j < dg)                // wave-uniform
                        acc = edge_quad(aa[j], xg[j][k], WA, WB, WC, WD, BR, acc);
            }
        }
        // root partial (own half-row), weights chunked from LDS
        const float* rp = h_in + (size_t)v * IN + (half << 4);
        float rpart = 0.f;
        #pragma unroll
        for (int k = 0; k < 4; ++k) {
            const float4 RO = *(const float4*)(wp + 5 * PSTRIDE + 4 * k);
            const float4 xr = *(const float4*)(rp + 4 * k);
            rpart = fmaf(xr.x, RO.x, rpart);
            rpart = fmaf(xr.y, RO.y, rpart);
            rpart = fmaf(xr.z, RO.z, rpart);
            rpart = fmaf(xr.w, RO.w, rpart);
        }
        float part = acc / fmaxf((float)dt, 1.f) + rpart;
        part += __shfl_down(part, 32);              // combine halves
        if (lane < 32) {
            float h = fmaxf(part + bo, 0.f);
            if (!HEAD) {
                h_out[(size_t)v * HID + o] = h;
            } else {
                float tt = lw[8704 + o];            // hb1
                #pragma unroll
                for (int i = 0; i < HID; ++i)
                    tt = fmaf(__shfl(h, i, 32), lw[7680 + i * 32 + o], tt);
                tt = fmaxf(tt, 0.f) * lw[8736 + o]; // hw2
                #pragma unroll
                for (int dd = 16; dd > 0; dd >>= 1)
                    tt += __shfl_down(tt, dd, 32);
                if (o == 0) h_out[v] = tt + hb2v;
            }
        }
    }
}

extern "C" void kernel_launch(void* const* d_in, const int* in_sizes, int n_in,
                              void* d_out, int out_size, void* d_ws, size_t ws_size,
                              hipStream_t stream)
{
    const float* x      = (const float*)d_in[0];
    const int*   ei     = (const int*)d_in[1];     // [2, E] int32
    const float* ea     = (const float*)d_in[2];
    const float* w_mlp1 = (const float*)d_in[3];
    const float* b_mlp1 = (const float*)d_in[4];
    const float* root1  = (const float*)d_in[5];
    const float* bias1  = (const float*)d_in[6];
    const float* w_mlp2 = (const float*)d_in[7];
    const float* b_mlp2 = (const float*)d_in[8];
    const float* root2  = (const float*)d_in[9];
    const float* bias2  = (const float*)d_in[10];
    const float* w_mlp3 = (const float*)d_in[11];
    const float* b_mlp3 = (const float*)d_in[12];
    const float* root3  = (const float*)d_in[13];
    const float* bias3  = (const float*)d_in[14];
    const float* w_out1 = (const float*)d_in[15];
    const float* b_out1 = (const float*)d_in[16];
    const float* w_out2 = (const float*)d_in[17];
    const float* b_out2 = (const float*)d_in[18];

    const int NODE_IN = 8;
    const int N = in_sizes[0] / NODE_IN;            // 25000
    const int E = in_sizes[2] / 4;                  // 100000
    const int* src = ei;
    const int* dst = ei + E;

    // workspace carve-up
    char* ws = (char*)d_ws;
    size_t off = 0;
    auto carve = [&](size_t bytes) {
        char* p = ws + off;
        off += (bytes + 255) & ~(size_t)255;
        return p;
    };
    int*    deg      = (int*)carve((size_t)N * 4);                  // 100 KB
    int*    perm_src = (int*)carve((size_t)N * CAP * 4);            // 3.2 MB
    float4* perm_ea  = (float4*)carve((size_t)N * CAP * 16);        // 12.8 MB
    float*  h1       = (float*)carve((size_t)N * HID * 4);          // 3.2 MB
    float*  h2       = (float*)carve((size_t)N * HID * 4);          // 3.2 MB
    float*  outp     = (float*)d_out;

    const int TB = 256;
    const int buildBlocks = (E + TB - 1) / TB;                      // 391
    // 4 waves/block, 8 nodes/wave -> 32 nodes/block
    const int pullBlocks = (N + 31) / 32;                           // 782

    // 1) zero deg only (100 KB)
    hipMemsetAsync(deg, 0, (size_t)N * 4, stream);

    // 2) build dst-bucketed edge permutation (reused by all 3 layers)
    build_kernel<<<buildBlocks, TB, 0, stream>>>(src, dst, ea, deg, perm_src, perm_ea, E);

    // 3) conv1: pull + fused node update  (x -> h1)
    pull8_kernel<<<pullBlocks, TB, 0, stream>>>(x, deg, perm_src, perm_ea,
                                                w_mlp1, b_mlp1, root1, bias1, h1, N);

    // 4) conv2: pull + fused node update  (h1 -> h2)
    pull32_kernel<false><<<pullBlocks, TB, 0, stream>>>(h1, deg, perm_src, perm_ea,
                                                        w_mlp2, b_mlp2, root2, bias2,
                                                        nullptr, nullptr, nullptr, nullptr, h2, N);

    // 5) conv3 + output head fused  (h2 -> out)
    pull32_kernel<true><<<pullBlocks, TB, 0, stream>>>(h2, deg, perm_src, perm_ea,
                                                       w_mlp3, b_mlp3, root3, bias3,
                                                       w_out1, b_out1, w_out2, b_out2, outp, N);
}

// Round 6
// 238.548 us; speedup vs baseline: 1.7278x; 1.7278x over previous
//
#include <hip/hip_runtime.h>

#define HID 32
#define CAP 32   // bucket capacity; indegree ~ Poisson(4), P(deg>32) ~ 1e-19

// ---- build dst-bucketed edge permutation (one pass, int atomics only) ----
// node v owns slots [v*CAP, v*CAP+deg[v]); perm_src zero-initialized by host-side
// memset, so slots >= deg hold node 0 (always safe to gather, gated at compute).
__global__ __launch_bounds__(256) void build_kernel(
    const int* __restrict__ src, const int* __restrict__ dst,
    const float* __restrict__ ea,
    int* __restrict__ deg, int* __restrict__ perm_src, float4* __restrict__ perm_ea,
    int E)
{
    int e = blockIdx.x * blockDim.x + threadIdx.x;
    if (e >= E) return;
    int d = dst[e];
    int pos = atomicAdd(deg + d, 1) & (CAP - 1);    // mask: memory-safe even on impossible overflow
    size_t slot = (size_t)d * CAP + pos;
    perm_src[slot] = src[e];
    perm_ea[slot]  = *(const float4*)(ea + (size_t)e * 4);
}

// ---- 4-input-channel quad of the fused edge-MLP + msg dot ----
// t_i = relu(ea . w[:,i,o] + b[i,o]);  acc += x_i * t_i   for 4 consecutive i
__device__ __forceinline__ float edge_quad(const float4 av, const float4 xv,
                                           const float4 WA, const float4 WB,
                                           const float4 WC, const float4 WD,
                                           const float4 BR, float acc)
{
    float t;
    t = fmaf(av.x, WA.x, BR.x); t = fmaf(av.y, WB.x, t); t = fmaf(av.z, WC.x, t); t = fmaf(av.w, WD.x, t);
    acc = fmaf(xv.x, fmaxf(t, 0.f), acc);
    t = fmaf(av.x, WA.y, BR.y); t = fmaf(av.y, WB.y, t); t = fmaf(av.z, WC.y, t); t = fmaf(av.w, WD.y, t);
    acc = fmaf(xv.y, fmaxf(t, 0.f), acc);
    t = fmaf(av.x, WA.z, BR.z); t = fmaf(av.y, WB.z, t); t = fmaf(av.z, WC.z, t); t = fmaf(av.w, WD.z, t);
    acc = fmaf(xv.z, fmaxf(t, 0.f), acc);
    t = fmaf(av.x, WA.w, BR.w); t = fmaf(av.y, WB.w, t); t = fmaf(av.z, WC.w, t); t = fmaf(av.w, WD.w, t);
    acc = fmaf(xv.w, fmaxf(t, 0.f), acc);
    return acc;
}

// ---- layer-1 pull (IN=8): 64-lane wave per node; o = lane&31, half = lane>>5
// owns input channels half*4..half*4+3. Weight state = 6 float4 = 24 regs ->
// pure-register. Small compute per edge -> rely on occupancy (6 waves/EU,
// NPG=4 gives 6250 waves) rather than deep per-wave pipelining.
__global__ __launch_bounds__(256, 6) void pull8_kernel(
    const float* __restrict__ x,                    // [N, 8]
    const int* __restrict__ deg,
    const int* __restrict__ perm_src, const float4* __restrict__ perm_ea,
    const float* __restrict__ w_mlp,                // [4, 8*HID]
    const float* __restrict__ b_mlp,                // [8*HID]
    const float* __restrict__ root,                 // [8, HID]
    const float* __restrict__ bias,                 // [HID]
    float* __restrict__ h_out,                      // [N, HID]
    int N)
{
    constexpr int IN = 8, NPG = 4;
    const int lane = threadIdx.x & 63;
    const int o = lane & 31, half = lane >> 5;
    const int wave = (blockIdx.x * blockDim.x + threadIdx.x) >> 6;
    const int v0 = wave * NPG;
    if (v0 >= N) return;

    const int cb = half * 4 * HID + o;              // i = half*4 + {0..3}; coalesced per load
    const float4 WA = make_float4(w_mlp[cb],       w_mlp[cb+32],       w_mlp[cb+64],       w_mlp[cb+96]);
    const float4 WB = make_float4(w_mlp[256+cb],   w_mlp[256+cb+32],   w_mlp[256+cb+64],   w_mlp[256+cb+96]);
    const float4 WC = make_float4(w_mlp[512+cb],   w_mlp[512+cb+32],   w_mlp[512+cb+64],   w_mlp[512+cb+96]);
    const float4 WD = make_float4(w_mlp[768+cb],   w_mlp[768+cb+32],   w_mlp[768+cb+64],   w_mlp[768+cb+96]);
    const float4 BR = make_float4(b_mlp[cb],       b_mlp[cb+32],       b_mlp[cb+64],       b_mlp[cb+96]);
    const float4 RO = make_float4(root[cb],        root[cb+32],        root[cb+64],        root[cb+96]);
    const float bo = bias[o];

    for (int nv = 0; nv < NPG; ++nv) {
        const int v = v0 + nv;
        if (v >= N) break;
        const int dt = deg[v];
        const int dg = min(dt, CAP);
        const int* ps = perm_src + (size_t)v * CAP;
        const float4* pe = perm_ea + (size_t)v * CAP;

        float acc = 0.f;
        for (int k0 = 0; k0 < dg; k0 += 4) {
            int4 s4 = *(const int4*)(ps + k0);      // stale slots = 0 (zero-init): safe
            const int ss[4] = { s4.x, s4.y, s4.z, s4.w };
            float4 aa[4];
            #pragma unroll
            for (int j = 0; j < 4; ++j) aa[j] = pe[k0 + j];
            float4 xg[4];
            #pragma unroll
            for (int j = 0; j < 4; ++j)
                xg[j] = *(const float4*)(x + (size_t)ss[j] * IN + half * 4);
            #pragma unroll
            for (int j = 0; j < 4; ++j)
                if (k0 + j < dg)                    // wave-uniform gate
                    acc = edge_quad(aa[j], xg[j], WA, WB, WC, WD, BR, acc);
        }
        const float4 xr = *(const float4*)(x + (size_t)v * IN + half * 4);
        float rpart = fmaf(xr.x, RO.x, fmaf(xr.y, RO.y, fmaf(xr.z, RO.z, xr.w * RO.w)));
        float part = acc / fmaxf((float)dt, 1.f) + rpart;
        part += __shfl_down(part, 32);              // combine halves
        if (lane < 32)
            h_out[(size_t)v * HID + o] = fmaxf(part + bo, 0.f);
    }
}

// ---- layers 2/3 pull (IN=32): 64-lane wave per node; o = lane&31, half = lane>>5
// owns 16 input channels. Register-resident weights (24 f4 = 96 VGPR).
// amdgpu_waves_per_eu(2,2) pins occupancy to 2 waves/EU so the allocator has no
// incentive to rematerialize weights (the R4 58µs failure mode at VGPR=120).
// Flattened 2-neighbor-batch pipeline: next batch's deg/src/ea/x-gathers issue
// during the current batch's ~384cy FMA block; own-row load issued at last-batch
// start (hidden under compute). HEAD fuses conv3 node update + output MLP.
template<bool HEAD>
__global__ __launch_bounds__(256) __attribute__((amdgpu_waves_per_eu(2, 2)))
void pull32_kernel(
    const float* __restrict__ h_in,                 // [N, 32]
    const int* __restrict__ deg,
    const int* __restrict__ perm_src, const float4* __restrict__ perm_ea,
    const float* __restrict__ w_mlp,                // [4, 32*HID]
    const float* __restrict__ b_mlp,                // [32*HID]
    const float* __restrict__ root,                 // [32, HID]
    const float* __restrict__ bias,                 // [HID]
    const float* __restrict__ hw1, const float* __restrict__ hb1,  // head
    const float* __restrict__ hw2, const float* __restrict__ hb2,  // head
    float* __restrict__ h_out,                      // [N, HID] or [N] if HEAD
    int N)
{
    constexpr int IN = 32, NPW = 8;
    const int lane = threadIdx.x & 63;
    const int o = lane & 31, half = lane >> 5;
    const int wave = (blockIdx.x * blockDim.x + threadIdx.x) >> 6;
    const int v0 = wave * NPW;
    if (v0 >= N) return;
    const int vEnd = min(v0 + NPW, N);
    const int hoff = half << 4;

    // this lane's weight column: 24 float4 = 96 VGPR, register-resident
    float4 WA[4], WB[4], WC[4], WD[4], BR[4], RO[4];
    #pragma unroll
    for (int k = 0; k < 4; ++k) {
        const int ib = (hoff + (k << 2)) * HID + o;
        WA[k] = make_float4(w_mlp[ib],      w_mlp[ib+32],      w_mlp[ib+64],      w_mlp[ib+96]);
        WB[k] = make_float4(w_mlp[1024+ib], w_mlp[1024+ib+32], w_mlp[1024+ib+64], w_mlp[1024+ib+96]);
        WC[k] = make_float4(w_mlp[2048+ib], w_mlp[2048+ib+32], w_mlp[2048+ib+64], w_mlp[2048+ib+96]);
        WD[k] = make_float4(w_mlp[3072+ib], w_mlp[3072+ib+32], w_mlp[3072+ib+64], w_mlp[3072+ib+96]);
        BR[k] = make_float4(b_mlp[ib],      b_mlp[ib+32],      b_mlp[ib+64],      b_mlp[ib+96]);
        RO[k] = make_float4(root[ib],       root[ib+32],       root[ib+64],       root[ib+96]);
    }
    const float bo = bias[o];

    // ---- prologue: batch (v0, 0) ----
    int vC = v0, k0C = 0;
    int dgC = deg[v0];
    float4 aC0 = perm_ea[(size_t)v0 * CAP];
    float4 aC1 = perm_ea[(size_t)v0 * CAP + 1];
    float4 xC0[4], xC1[4];
    {
        const int2 s2 = *(const int2*)(perm_src + (size_t)v0 * CAP);  // zero-init: always valid ids
        const float* p0 = h_in + (size_t)s2.x * IN + hoff;
        const float* p1 = h_in + (size_t)s2.y * IN + hoff;
        #pragma unroll
        for (int q = 0; q < 4; ++q) { xC0[q] = *(const float4*)(p0 + 4*q); xC1[q] = *(const float4*)(p1 + 4*q); }
    }
    float acc = 0.f;

    #pragma unroll 2
    for (;;) {
        const int dgCc = min(dgC, CAP);
        const bool lastB = (k0C + 2 >= dgCc);
        const int vN  = lastB ? vC + 1 : vC;
        const int k0N = lastB ? 0 : k0C + 2;
        const bool haveN = (vN < vEnd);

        // ---- prefetch next batch (lands under this batch's compute) ----
        int dgN = 0;
        float4 aN0, aN1, xN0[4], xN1[4];
        if (haveN) {
            dgN = deg[vN];                          // independent of gather chain
            const int2 s2N = *(const int2*)(perm_src + (size_t)vN * CAP + k0N);
            aN0 = perm_ea[(size_t)vN * CAP + k0N];
            aN1 = perm_ea[(size_t)vN * CAP + k0N + 1];
            const float* p0 = h_in + (size_t)s2N.x * IN + hoff;
            const float* p1 = h_in + (size_t)s2N.y * IN + hoff;
            #pragma unroll
            for (int q = 0; q < 4; ++q) { xN0[q] = *(const float4*)(p0 + 4*q); xN1[q] = *(const float4*)(p1 + 4*q); }
        }

        // own-row for finalize: issued before the FMA block, ~300cy hidden
        float4 rC[4];
        if (lastB) {
            const float* rp = h_in + (size_t)vC * IN + hoff;
            #pragma unroll
            for (int q = 0; q < 4; ++q) rC[q] = *(const float4*)(rp + 4*q);
        }

        // ---- compute current batch (wave-uniform gates; stale aa never used) ----
        if (k0C < dgCc) {
            #pragma unroll
            for (int k = 0; k < 4; ++k)
                acc = edge_quad(aC0, xC0[k], WA[k], WB[k], WC[k], WD[k], BR[k], acc);
        }
        if (k0C + 1 < dgCc) {
            #pragma unroll
            for (int k = 0; k < 4; ++k)
                acc = edge_quad(aC1, xC1[k], WA[k], WB[k], WC[k], WD[k], BR[k], acc);
        }

        // ---- finalize node on its last batch ----
        if (lastB) {
            float rpart = 0.f;
            #pragma unroll
            for (int k = 0; k < 4; ++k) {
                rpart = fmaf(rC[k].x, RO[k].x, rpart);
                rpart = fmaf(rC[k].y, RO[k].y, rpart);
                rpart = fmaf(rC[k].z, RO[k].z, rpart);
                rpart = fmaf(rC[k].w, RO[k].w, rpart);
            }
            float part = acc / fmaxf((float)dgC, 1.f) + rpart;
            part += __shfl_down(part, 32);          // combine i-halves
            if (lane < 32) {
                float h = fmaxf(part + bo, 0.f);
                if (!HEAD) {
                    h_out[(size_t)vC * HID + o] = h;
                } else {
                    float tt = hb1[o];
                    #pragma unroll
                    for (int i = 0; i < HID; ++i)
                        tt = fmaf(__shfl(h, i, 32), hw1[i * HID + o], tt);
                    tt = fmaxf(tt, 0.f) * hw2[o];
                    #pragma unroll
                    for (int dd = 16; dd > 0; dd >>= 1)
                        tt += __shfl_down(tt, dd, 32);
                    if (o == 0) h_out[vC] = tt + hb2[0];
                }
            }
            acc = 0.f;
        }

        if (!haveN) break;
        vC = vN; k0C = k0N; dgC = dgN;
        aC0 = aN0; aC1 = aN1;
        #pragma unroll
        for (int q = 0; q < 4; ++q) { xC0[q] = xN0[q]; xC1[q] = xN1[q]; }
    }
}

extern "C" void kernel_launch(void* const* d_in, const int* in_sizes, int n_in,
                              void* d_out, int out_size, void* d_ws, size_t ws_size,
                              hipStream_t stream)
{
    const float* x      = (const float*)d_in[0];
    const int*   ei     = (const int*)d_in[1];     // [2, E] int32
    const float* ea     = (const float*)d_in[2];
    const float* w_mlp1 = (const float*)d_in[3];
    const float* b_mlp1 = (const float*)d_in[4];
    const float* root1  = (const float*)d_in[5];
    const float* bias1  = (const float*)d_in[6];
    const float* w_mlp2 = (const float*)d_in[7];
    const float* b_mlp2 = (const float*)d_in[8];
    const float* root2  = (const float*)d_in[9];
    const float* bias2  = (const float*)d_in[10];
    const float* w_mlp3 = (const float*)d_in[11];
    const float* b_mlp3 = (const float*)d_in[12];
    const float* root3  = (const float*)d_in[13];
    const float* bias3  = (const float*)d_in[14];
    const float* w_out1 = (const float*)d_in[15];
    const float* b_out1 = (const float*)d_in[16];
    const float* w_out2 = (const float*)d_in[17];
    const float* b_out2 = (const float*)d_in[18];

    const int NODE_IN = 8;
    const int N = in_sizes[0] / NODE_IN;            // 25000
    const int E = in_sizes[2] / 4;                  // 100000
    const int* src = ei;
    const int* dst = ei + E;

    // workspace carve-up (deg and perm_src adjacent: one memset zeroes both)
    char* ws = (char*)d_ws;
    size_t off = 0;
    auto carve = [&](size_t bytes) {
        char* p = ws + off;
        off += (bytes + 255) & ~(size_t)255;
        return p;
    };
    int*    deg      = (int*)carve((size_t)N * 4);                  // 100 KB
    int*    perm_src = (int*)carve((size_t)N * CAP * 4);            // 3.2 MB
    float4* perm_ea  = (float4*)carve((size_t)N * CAP * 16);        // 12.8 MB
    float*  h1       = (float*)carve((size_t)N * HID * 4);          // 3.2 MB
    float*  h2       = (float*)carve((size_t)N * HID * 4);          // 3.2 MB
    float*  outp     = (float*)d_out;
    size_t zero_bytes = (size_t)((char*)perm_src - (char*)deg) + (size_t)N * CAP * 4;

    const int TB = 256;
    const int buildBlocks = (E + TB - 1) / TB;                      // 391
    const int p8Blocks  = (N + 4 * 4 - 1) / (4 * 4);                // NPG=4, 4 waves/block -> 1563
    const int p32Blocks = (N + 8 * 4 - 1) / (8 * 4);                // NPW=8, 4 waves/block -> 782

    // 1) zero deg + perm_src (3.3 MB; stale perm_src slots must be node 0)
    hipMemsetAsync(deg, 0, zero_bytes, stream);

    // 2) build dst-bucketed edge permutation (reused by all 3 layers)
    build_kernel<<<buildBlocks, TB, 0, stream>>>(src, dst, ea, deg, perm_src, perm_ea, E);

    // 3) conv1: pull + fused node update  (x -> h1)
    pull8_kernel<<<p8Blocks, TB, 0, stream>>>(x, deg, perm_src, perm_ea,
                                              w_mlp1, b_mlp1, root1, bias1, h1, N);

    // 4) conv2: pull + fused node update  (h1 -> h2)
    pull32_kernel<false><<<p32Blocks, TB, 0, stream>>>(h1, deg, perm_src, perm_ea,
                                                       w_mlp2, b_mlp2, root2, bias2,
                                                       nullptr, nullptr, nullptr, nullptr, h2, N);

    // 5) conv3 + output head fused  (h2 -> out)
    pull32_kernel<true><<<p32Blocks, TB, 0, stream>>>(h2, deg, perm_src, perm_ea,
                                                      w_mlp3, b_mlp3, root3, bias3,
                                                      w_out1, b_out1, w_out2, b_out2, outp, N);
}